// Round 2
// baseline (543.486 us; speedup 1.0000x reference)
//
#include <hip/hip_runtime.h>
#include <hip/hip_bf16.h>
#include <cstdint>
#include <cstddef>

#define B_ 4
#define L_ 8192
#define D_ 512
#define H_ 1024
#define NC_ 32            // chunks along L for the 3-phase scan
#define LC_ (L_ / NC_)    // 256

typedef float  f32x4 __attribute__((ext_vector_type(4)));
typedef short  s16x8 __attribute__((ext_vector_type(8)));
typedef __bf16 b16x8 __attribute__((ext_vector_type(8)));

// ---- MFMA wrapper: tolerate either builtin signature (v8i16 or v8bf16) ----
template <typename T, typename U>
__device__ inline auto mfma_sel(T a, T b, f32x4 c, U, int)
    -> decltype(__builtin_amdgcn_mfma_f32_16x16x32_bf16(a, b, c, 0, 0, 0)) {
  return __builtin_amdgcn_mfma_f32_16x16x32_bf16(a, b, c, 0, 0, 0);
}
template <typename T, typename U>
__device__ inline f32x4 mfma_sel(T a, T b, f32x4 c, U, long) {
  return __builtin_amdgcn_mfma_f32_16x16x32_bf16(
      __builtin_bit_cast(U, a), __builtin_bit_cast(U, b), c, 0, 0, 0);
}
__device__ inline f32x4 mfma_bf16_16x16x32(s16x8 a, s16x8 b, f32x4 c) {
  return mfma_sel(a, b, c, b16x8{}, 0);
}

// ---- fp32 <-> bf16 ----
__device__ inline ushort f2bf(float f) {
  uint32_t u = __builtin_bit_cast(uint32_t, f);
  uint32_t r = (u + 0x7fffu + ((u >> 16) & 1u)) >> 16;
  return (ushort)r;
}
__device__ inline float bf2f(ushort u) {
  return __builtin_bit_cast(float, (uint32_t)u << 16);
}

__global__ void cast_kernel(const float* __restrict__ in, ushort* __restrict__ out, int n4) {
  int i = blockIdx.x * blockDim.x + threadIdx.x;
  if (i >= n4) return;
  float4 f = reinterpret_cast<const float4*>(in)[i];
  ushort4 o;
  o.x = f2bf(f.x); o.y = f2bf(f.y); o.z = f2bf(f.z); o.w = f2bf(f.w);
  reinterpret_cast<ushort4*>(out)[i] = o;
}

// ---- NT GEMM: C[m][n] = sum_k A[m][k]*Bm[n][k] + bias[n]; A:MxK, Bm:NxK (row-major bf16) ----
// 128x128 tile, BK=32, 4 waves (2x2), each wave 64x64 via 4x4 MFMA 16x16x32 tiles.
// OUT_BF16: C is ushort* (bf16), else float*.
template <bool OUT_BF16>
__global__ __launch_bounds__(256)
void gemm_bt(const ushort* __restrict__ A, const ushort* __restrict__ Bm,
             const float* __restrict__ bias, void* __restrict__ Cv,
             int M, int N, int K) {
  __shared__ ushort As[128 * 32];
  __shared__ ushort Bs[128 * 32];
  const int tid  = threadIdx.x;
  const int wave = tid >> 6;
  const int lane = tid & 63;
  const int l15  = lane & 15;
  const int quad = lane >> 4;
  const long bm = (long)blockIdx.y * 128;
  const long bn = (long)blockIdx.x * 128;
  const int  wm = (wave >> 1) * 64;
  const int  wn = (wave & 1) * 64;

  f32x4 acc[4][4];
#pragma unroll
  for (int i = 0; i < 4; ++i)
#pragma unroll
    for (int j = 0; j < 4; ++j) acc[i][j] = (f32x4){0.f, 0.f, 0.f, 0.f};

  // staging: wave fills rows [wave*32, wave*32+32) of As/Bs; lane -> (row, 8-elem col)
  const int srow = wave * 32 + (lane >> 2);
  const int scol = (lane & 3) * 8;
  const ushort* gA0 = A  + (bm + srow) * (long)K + scol;
  const ushort* gB0 = Bm + (bn + srow) * (long)K + scol;
  ushort* lA0 = &As[(wave * 32) * 32];
  ushort* lA1 = &As[(wave * 32 + 16) * 32];
  ushort* lB0 = &Bs[(wave * 32) * 32];
  ushort* lB1 = &Bs[(wave * 32 + 16) * 32];

  for (int k0 = 0; k0 < K; k0 += 32) {
    __builtin_amdgcn_global_load_lds(
        (const __attribute__((address_space(1))) void*)(gA0 + k0),
        (__attribute__((address_space(3))) void*)lA0, 16, 0, 0);
    __builtin_amdgcn_global_load_lds(
        (const __attribute__((address_space(1))) void*)(gA0 + 16L * K + k0),
        (__attribute__((address_space(3))) void*)lA1, 16, 0, 0);
    __builtin_amdgcn_global_load_lds(
        (const __attribute__((address_space(1))) void*)(gB0 + k0),
        (__attribute__((address_space(3))) void*)lB0, 16, 0, 0);
    __builtin_amdgcn_global_load_lds(
        (const __attribute__((address_space(1))) void*)(gB0 + 16L * K + k0),
        (__attribute__((address_space(3))) void*)lB1, 16, 0, 0);
    __syncthreads();   // drains vmcnt -> LDS tile ready

    s16x8 af[4], bf[4];
#pragma unroll
    for (int mi = 0; mi < 4; ++mi)
      af[mi] = *reinterpret_cast<const s16x8*>(&As[(wm + mi * 16 + l15) * 32 + quad * 8]);
#pragma unroll
    for (int ni = 0; ni < 4; ++ni)
      bf[ni] = *reinterpret_cast<const s16x8*>(&Bs[(wn + ni * 16 + l15) * 32 + quad * 8]);
#pragma unroll
    for (int mi = 0; mi < 4; ++mi)
#pragma unroll
      for (int ni = 0; ni < 4; ++ni)
        acc[mi][ni] = mfma_bf16_16x16x32(af[mi], bf[ni], acc[mi][ni]);
    __syncthreads();   // protect LDS before next stage
  }

  // epilogue: C/D layout col = lane&15, row = quad*4 + reg
#pragma unroll
  for (int mi = 0; mi < 4; ++mi) {
    const long mrow = bm + wm + mi * 16 + quad * 4;
#pragma unroll
    for (int ni = 0; ni < 4; ++ni) {
      const long ncol = bn + wn + ni * 16 + l15;
      const float bv = bias[ncol];
      if (OUT_BF16) {
        ushort* cp = (ushort*)Cv + mrow * (long)N + ncol;
#pragma unroll
        for (int r = 0; r < 4; ++r) cp[(long)r * N] = f2bf(acc[mi][ni][r] + bv);
      } else {
        float* cp = (float*)Cv + mrow * (long)N + ncol;
#pragma unroll
        for (int r = 0; r < 4; ++r) cp[(long)r * N] = acc[mi][ni][r] + bv;
      }
    }
  }
}

// ---- scan helpers ----
__device__ inline float softplus_f(float x) {
  return fmaxf(x, 0.f) + __logf(1.f + __expf(-fabsf(x)));
}
__device__ inline float logaddexp_f(float a, float b) {
  float m = fmaxf(a, b);
  return m + __logf(1.f + __expf(-fabsf(a - b)));
}
// from (hidden, gate): lc = -softplus(g); v = log_z + log_tilde_h
__device__ inline void transform_f(float hd, float g, float& lc, float& v) {
  float sp = softplus_f(g);
  lc = -sp;
  float lz = g - sp;                       // -softplus(-g)
  float lth = (hd >= 0.f) ? __logf(hd + 0.5f) : (hd - softplus_f(hd));
  v = lz + lth;
}

// phase 1: per (b, chunk, h) compute chunk composition (Asum, Bv)
__global__ void scan_phase1(const ushort* __restrict__ hg,
                            float* __restrict__ Ac, float* __restrict__ Bc) {
  int gid = blockIdx.x * blockDim.x + threadIdx.x;  // B_*NC_*H_
  int h = gid & (H_ - 1);
  int c = (gid >> 10) & (NC_ - 1);
  int b = gid >> 15;
  const ushort* p = hg + ((size_t)(b * L_ + c * LC_) * (2 * H_)) + h;
  float Asum = 0.f, Bv = -INFINITY;
#pragma unroll 4
  for (int l = 0; l < LC_; ++l) {
    float hd = bf2f(p[0]), g = bf2f(p[H_]);
    float lc, v; transform_f(hd, g, lc, v);
    Asum += lc;
    Bv = logaddexp_f(Bv + lc, v);
    p += 2 * H_;
  }
  int o = (b * NC_ + c) * H_ + h;
  Ac[o] = Asum; Bc[o] = Bv;
}

// phase 2: per (b, h) exclusive scan over chunk summaries -> carry (incoming log_h per chunk)
__global__ void scan_phase2(const float* __restrict__ Ac, const float* __restrict__ Bc,
                            float* __restrict__ carry) {
  int gid = blockIdx.x * blockDim.x + threadIdx.x;  // B_*H_
  int h = gid & (H_ - 1);
  int b = gid >> 10;
  float P = -INFINITY;
  for (int c = 0; c < NC_; ++c) {
    int o = (b * NC_ + c) * H_ + h;
    carry[o] = P;
    P = logaddexp_f(P + Ac[o], Bc[o]);
  }
}

// phase 3: re-scan chunk with carry, emit h = exp(log_h) as bf16
__global__ void scan_phase3(const ushort* __restrict__ hg, const float* __restrict__ carry,
                            ushort* __restrict__ hb) {
  int gid = blockIdx.x * blockDim.x + threadIdx.x;  // B_*NC_*H_
  int h = gid & (H_ - 1);
  int c = (gid >> 10) & (NC_ - 1);
  int b = gid >> 15;
  float lh = carry[(b * NC_ + c) * H_ + h];
  const ushort* p = hg + ((size_t)(b * L_ + c * LC_) * (2 * H_)) + h;
  ushort* q = hb + (size_t)(b * L_ + c * LC_) * H_ + h;
#pragma unroll 4
  for (int l = 0; l < LC_; ++l) {
    float hd = bf2f(p[0]), g = bf2f(p[H_]);
    float lc, v; transform_f(hd, g, lc, v);
    lh = logaddexp_f(lh + lc, v);
    *q = f2bf(__expf(lh));
    p += 2 * H_;
    q += H_;
  }
}

extern "C" void kernel_launch(void* const* d_in, const int* in_sizes, int n_in,
                              void* d_out, int out_size, void* d_ws, size_t ws_size,
                              hipStream_t stream) {
  const float* x     = (const float*)d_in[0];
  const float* W_in  = (const float*)d_in[1];
  const float* b_in  = (const float*)d_in[2];
  const float* W_out = (const float*)d_in[3];
  const float* b_out = (const float*)d_in[4];
  float* out = (float*)d_out;

  char* ws = (char*)d_ws;
  size_t off = 0;
  auto alloc = [&](size_t bytes) {
    void* p = ws + off;
    off = (off + bytes + 255) & ~(size_t)255;
    return p;
  };
  // region shared by xb (alive: cast -> GEMM1) and hb (alive: phase3 -> GEMM2)
  ushort* xb    = (ushort*)alloc((size_t)B_ * L_ * H_ * 2);       // 67 MB (union)
  ushort* hb    = xb;
  ushort* Wib   = (ushort*)alloc((size_t)2 * H_ * D_ * 2);        // 2 MB
  ushort* Wob   = (ushort*)alloc((size_t)D_ * H_ * 2);            // 1 MB
  ushort* hgb   = (ushort*)alloc((size_t)B_ * L_ * 2 * H_ * 2);   // 134 MB (bf16)
  float*  Ac    = (float*)alloc((size_t)B_ * NC_ * H_ * 4);
  float*  Bc    = (float*)alloc((size_t)B_ * NC_ * H_ * 4);
  float*  carry = (float*)alloc((size_t)B_ * NC_ * H_ * 4);
  // total ~206 MB

  // casts to bf16
  cast_kernel<<<(B_ * L_ * D_ / 4 + 255) / 256, 256, 0, stream>>>(x, xb, B_ * L_ * D_ / 4);
  cast_kernel<<<(2 * H_ * D_ / 4 + 255) / 256, 256, 0, stream>>>(W_in, Wib, 2 * H_ * D_ / 4);
  cast_kernel<<<(D_ * H_ / 4 + 255) / 256, 256, 0, stream>>>(W_out, Wob, D_ * H_ / 4);

  // GEMM1: hg = x . W_in^T + b_in   (M=32768, N=2048, K=512), bf16 out
  gemm_bt<true><<<dim3((2 * H_) / 128, (B_ * L_) / 128), 256, 0, stream>>>(
      xb, Wib, b_in, hgb, B_ * L_, 2 * H_, D_);

  // chunked scan along L
  scan_phase1<<<(B_ * NC_ * H_) / 256, 256, 0, stream>>>(hgb, Ac, Bc);
  scan_phase2<<<(B_ * H_) / 256, 256, 0, stream>>>(Ac, Bc, carry);
  scan_phase3<<<(B_ * NC_ * H_) / 256, 256, 0, stream>>>(hgb, carry, hb);

  // GEMM2: out = h . W_out^T + b_out   (M=32768, N=512, K=1024), fp32 out
  gemm_bt<false><<<dim3(D_ / 128, (B_ * L_) / 128), 256, 0, stream>>>(
      hb, Wob, b_out, out, B_ * L_, D_, H_);
}